// Round 1
// baseline (1539.855 us; speedup 1.0000x reference)
//
#include <hip/hip_runtime.h>

// ---------------------------------------------------------------------------
// Swin block: LN1 -> shift+window -> QKV -> win-attn(+relbias+mask) -> proj
//             -> reverse+residual -> LN2 -> MLP(GELU) -> residual
// B=16 H=W=64 C=256 WS=8 SHIFT=4 HEADS=8 HD=32 N=64 HID=1024
// Round 0: correctness-first. f32 tiled GEMMs, bf16 staging of intermediates.
// Workspace: 32MB (xw/attn_out/ln2out) + 128MB (qkv/hidden) + 64MB (h2)
//            + 128KB (bias expand) = ~224 MiB
// ---------------------------------------------------------------------------

__device__ __forceinline__ float bf2f(unsigned short h) {
    union { unsigned int u; float f; } c; c.u = ((unsigned int)h) << 16; return c.f;
}
__device__ __forceinline__ unsigned short f2bf(float f) {
    union { float f; unsigned int u; } c; c.f = f;
    unsigned int u = c.u;
    return (unsigned short)((u + 0x7FFFu + ((u >> 16) & 1u)) >> 16);
}
// window-order row (b, wi, wj, r, cc) -> pixel-order row (b, hp, wp).
// Same map for the LN1 gather (roll -4) and proj scatter (roll +4).
__device__ __forceinline__ int remap_row(int row) {
    int b  = row >> 12;
    int w6 = (row >> 6) & 63;
    int n  = row & 63;
    int hp = (((w6 >> 3) << 3) + (n >> 3) + 4) & 63;
    int wp = (((w6 & 7) << 3) + (n & 7) + 4) & 63;
    return (b << 12) | (hp << 6) | wp;
}
__device__ __forceinline__ float gelu_f(float v) {
    float c = v + 0.044715f * v * v * v;
    return 0.5f * v * (1.0f + tanhf(0.7978845608028654f * c));
}

// ---- LayerNorm over C=256; one wave per row; optional gather remap --------
__global__ __launch_bounds__(256) void ln_kernel(
    const float* __restrict__ in, const float* __restrict__ g,
    const float* __restrict__ b, unsigned short* __restrict__ out, int remap)
{
    int wave = threadIdx.x >> 6, lane = threadIdx.x & 63;
    int row = (blockIdx.x << 2) + wave;
    int src = remap ? remap_row(row) : row;
    float4 xv = *(const float4*)(in + (size_t)src * 256 + (lane << 2));
    float s  = xv.x + xv.y + xv.z + xv.w;
    float ss = xv.x*xv.x + xv.y*xv.y + xv.z*xv.z + xv.w*xv.w;
#pragma unroll
    for (int off = 32; off; off >>= 1) {
        s  += __shfl_xor(s,  off, 64);
        ss += __shfl_xor(ss, off, 64);
    }
    float mu  = s * (1.0f / 256.0f);
    float inv = rsqrtf(ss * (1.0f / 256.0f) - mu * mu + 1e-5f);
    float4 gv = *(const float4*)(g + (lane << 2));
    float4 bv = *(const float4*)(b + (lane << 2));
    ushort4 o;
    o.x = f2bf((xv.x - mu) * inv * gv.x + bv.x);
    o.y = f2bf((xv.y - mu) * inv * gv.y + bv.y);
    o.z = f2bf((xv.z - mu) * inv * gv.z + bv.z);
    o.w = f2bf((xv.w - mu) * inv * gv.w + bv.w);
    *(ushort4*)(out + (size_t)row * 256 + (lane << 2)) = o;
}

// ---- expand rel-pos bias to [head][m][n] for coalesced attn reads ---------
__global__ __launch_bounds__(256) void bias_expand_kernel(
    const float* __restrict__ table, const int* __restrict__ relidx,
    float* __restrict__ out)
{
    int i = blockIdx.x * 256 + threadIdx.x;   // 8*64*64 = 32768
    int head = i >> 12;
    int m = (i >> 6) & 63;
    int n = i & 63;
    out[i] = table[relidx[n * 64 + m] * 8 + head];
}

// ---- tiled f32 GEMM, A is bf16 [M,K], B is f32 [K,N] ----------------------
// OUT_BF16: write bf16 (else f32 with residual add)
// DO_GELU : apply tanh-GELU in epilogue
// RESID   : 0 none, 1 resid[row] same-row, 2 row->remap_row, resid at remapped
template<int OUT_BF16, int DO_GELU, int RESID>
__global__ __launch_bounds__(256) void gemm_kernel(
    const unsigned short* __restrict__ A, const float* __restrict__ B,
    const float* __restrict__ bias, void* __restrict__ outp,
    const float* __restrict__ resid, int M, int N, int K)
{
    __shared__ float As[16][64];
    __shared__ float Bs[16][64];
    const int nb = N >> 6;
    const int m0 = (blockIdx.x / nb) << 6;
    const int n0 = (blockIdx.x % nb) << 6;
    const int tid = threadIdx.x;
    const int tr = tid >> 4, tc = tid & 15;

    const int arow = tid >> 2;          // 0..63
    const int ak   = (tid & 3) << 2;    // 0,4,8,12
    const int bk   = tid >> 4;          // 0..15
    const int bn4  = (tid & 15) << 2;   // 0..60

    float acc[4][4] = {};
    for (int k0 = 0; k0 < K; k0 += 16) {
        ushort4 av = *(const ushort4*)(A + (size_t)(m0 + arow) * K + k0 + ak);
        float4  bv = *(const float4*)(B + (size_t)(k0 + bk) * N + n0 + bn4);
        As[ak + 0][arow] = bf2f(av.x);
        As[ak + 1][arow] = bf2f(av.y);
        As[ak + 2][arow] = bf2f(av.z);
        As[ak + 3][arow] = bf2f(av.w);
        *(float4*)&Bs[bk][bn4] = bv;
        __syncthreads();
#pragma unroll
        for (int k = 0; k < 16; ++k) {
            float4 a4 = *(const float4*)&As[k][tr << 2];
            float4 b4 = *(const float4*)&Bs[k][tc << 2];
            float ar[4] = {a4.x, a4.y, a4.z, a4.w};
            float br[4] = {b4.x, b4.y, b4.z, b4.w};
#pragma unroll
            for (int i = 0; i < 4; ++i)
#pragma unroll
                for (int j = 0; j < 4; ++j)
                    acc[i][j] += ar[i] * br[j];
        }
        __syncthreads();
    }
#pragma unroll
    for (int i = 0; i < 4; ++i) {
        int row = m0 + (tr << 2) + i;
        int orow = (RESID == 2) ? remap_row(row) : row;
#pragma unroll
        for (int j = 0; j < 4; ++j) {
            int col = n0 + (tc << 2) + j;
            float v = acc[i][j] + bias[col];
            if (DO_GELU) v = gelu_f(v);
            if (OUT_BF16) {
                ((unsigned short*)outp)[(size_t)row * N + col] = f2bf(v);
            } else {
                float r = RESID ? resid[(size_t)orow * N + col] : 0.0f;
                ((float*)outp)[(size_t)orow * N + col] = r + v;
            }
        }
    }
}

// ---- window attention: one (window, head) per 64-thread block -------------
// qkv: bf16 [65536, 768] with cols [q(0:256) | k(256:512) | v(512:768)],
//      within each: head*32 + hd.  out: bf16 [65536, 256] token-major.
__global__ __launch_bounds__(64) void attn_kernel(
    const unsigned short* __restrict__ qkv,
    const float* __restrict__ biasT,       // [head][m][n]
    unsigned short* __restrict__ out)
{
    __shared__ float kt[64][32];
    __shared__ float vt[64][32];
    __shared__ int reg[64];
    const int widx = blockIdx.x >> 3;
    const int head = blockIdx.x & 7;
    const int n = threadIdx.x;

    // shifted-window region id for the attention mask
    {
        int w6 = widx & 63;
        int ph = ((w6 >> 3) << 3) + (n >> 3);
        int pw = ((w6 & 7) << 3) + (n & 7);
        int rh = (ph < 56) ? 0 : ((ph < 60) ? 1 : 2);
        int rw = (pw < 56) ? 0 : ((pw < 60) ? 1 : 2);
        reg[n] = rh * 3 + rw;
    }

    const size_t rowbase = ((size_t)widx * 64 + n) * 768 + head * 32;
    float q[32];
#pragma unroll
    for (int d = 0; d < 32; ++d) {
        q[d]     = bf2f(qkv[rowbase + d]) * 0.17677669529663687f;
        kt[n][d] = bf2f(qkv[rowbase + 256 + d]);
        vt[n][d] = bf2f(qkv[rowbase + 512 + d]);
    }
    __syncthreads();

    const float* bh = biasT + head * 4096 + n;   // [m*64 + n], coalesced in n
    const int myreg = reg[n];
    float s[64];
    float mx = -1e30f;
#pragma unroll
    for (int m = 0; m < 64; ++m) {
        float sum = 0.f;
#pragma unroll
        for (int d4 = 0; d4 < 8; ++d4) {
            float4 kv = *(const float4*)&kt[m][d4 << 2];
            sum += q[(d4 << 2) + 0] * kv.x + q[(d4 << 2) + 1] * kv.y
                 + q[(d4 << 2) + 2] * kv.z + q[(d4 << 2) + 3] * kv.w;
        }
        sum += bh[m * 64];
        if (myreg != reg[m]) sum -= 100.0f;
        s[m] = sum;
        mx = fmaxf(mx, sum);
    }
    float denom = 0.f;
#pragma unroll
    for (int m = 0; m < 64; ++m) { s[m] = __expf(s[m] - mx); denom += s[m]; }
    const float inv = 1.0f / denom;

    float o[32] = {};
#pragma unroll
    for (int m = 0; m < 64; ++m) {
        float p = s[m];
#pragma unroll
        for (int d4 = 0; d4 < 8; ++d4) {
            float4 vv = *(const float4*)&vt[m][d4 << 2];
            o[(d4 << 2) + 0] += p * vv.x;
            o[(d4 << 2) + 1] += p * vv.y;
            o[(d4 << 2) + 2] += p * vv.z;
            o[(d4 << 2) + 3] += p * vv.w;
        }
    }
    unsigned short* orow = out + ((size_t)widx * 64 + n) * 256 + head * 32;
#pragma unroll
    for (int d = 0; d < 32; ++d) orow[d] = f2bf(o[d] * inv);
}

// ---------------------------------------------------------------------------
extern "C" void kernel_launch(void* const* d_in, const int* in_sizes, int n_in,
                              void* d_out, int out_size, void* d_ws, size_t ws_size,
                              hipStream_t stream)
{
    const float* x      = (const float*)d_in[0];
    const float* ln1_g  = (const float*)d_in[1];
    const float* ln1_b  = (const float*)d_in[2];
    const float* qkv_w  = (const float*)d_in[3];
    const float* qkv_b  = (const float*)d_in[4];
    const float* proj_w = (const float*)d_in[5];
    const float* proj_b = (const float*)d_in[6];
    const float* table  = (const float*)d_in[7];
    const float* ln2_g  = (const float*)d_in[8];
    const float* ln2_b  = (const float*)d_in[9];
    const float* w1     = (const float*)d_in[10];
    const float* b1     = (const float*)d_in[11];
    const float* w2     = (const float*)d_in[12];
    const float* b2     = (const float*)d_in[13];
    const int*   relidx = (const int*)d_in[14];
    float* out = (float*)d_out;

    char* w = (char*)d_ws;
    unsigned short* xw   = (unsigned short*)w;                            // 32MB: xw -> attn_out -> ln2out
    unsigned short* qkvb = (unsigned short*)(w + 33554432);               // 128MB: qkv -> mlp hidden
    float*          h2   = (float*)(w + 33554432 + 134217728);            // 64MB
    float*          bexp = (float*)(w + 33554432 + 134217728 + 67108864); // 128KB

    // 1. LN1 + cyclic shift + window partition (gather) -> xw bf16 [65536,256]
    ln_kernel<<<16384, 256, 0, stream>>>(x, ln1_g, ln1_b, xw, 1);
    // 1b. expand relative-position bias to [head][m][n]
    bias_expand_kernel<<<128, 256, 0, stream>>>(table, relidx, bexp);
    // 2. QKV GEMM -> qkvb bf16 [65536,768]
    gemm_kernel<1, 0, 0><<<12288, 256, 0, stream>>>(xw, qkv_w, qkv_b, (void*)qkvb,
                                                    nullptr, 65536, 768, 256);
    // 3. window attention -> attn_out (reuse xw) bf16 [65536,256]
    attn_kernel<<<8192, 64, 0, stream>>>(qkvb, bexp, xw);
    // 4. proj GEMM + window-reverse/unshift scatter + residual(x) -> h2 f32
    gemm_kernel<0, 0, 2><<<4096, 256, 0, stream>>>(xw, proj_w, proj_b, (void*)h2,
                                                   x, 65536, 256, 256);
    // 5. LN2 -> ln2out (reuse xw) bf16
    ln_kernel<<<16384, 256, 0, stream>>>(h2, ln2_g, ln2_b, xw, 0);
    // 6. MLP1 GEMM + GELU -> hidden (reuse qkvb) bf16 [65536,1024]
    gemm_kernel<1, 1, 0><<<16384, 256, 0, stream>>>(xw, w1, b1, (void*)qkvb,
                                                    nullptr, 65536, 1024, 256);
    // 7. MLP2 GEMM + residual(h2) -> d_out f32
    gemm_kernel<0, 0, 1><<<4096, 256, 0, stream>>>(qkvb, w2, b2, (void*)out,
                                                   h2, 65536, 256, 1024);
}

// Round 2
// 549.140 us; speedup vs baseline: 2.8041x; 2.8041x over previous
//
#include <hip/hip_runtime.h>

// ---------------------------------------------------------------------------
// Swin block: LN1 -> shift+window -> QKV -> win-attn(+relbias+mask) -> proj
//             -> reverse+residual -> LN2 -> MLP(GELU) -> residual
// B=16 H=W=64 C=256 WS=8 SHIFT=4 HEADS=8 HD=32 N=64 HID=1024
// Round 1: all four GEMMs -> MFMA bf16 (m97 structure: 128x128 tile, BK=32,
//          global_load_lds width 16, 4 waves x 4x4 16x16x32 fragments).
//          Weights transposed+bf16-converted on device each launch.
// ---------------------------------------------------------------------------

typedef __attribute__((ext_vector_type(8))) short bf16x8;
typedef __attribute__((ext_vector_type(4))) float f32x4;

__device__ __forceinline__ float bf2f(unsigned short h) {
    union { unsigned int u; float f; } c; c.u = ((unsigned int)h) << 16; return c.f;
}
__device__ __forceinline__ unsigned short f2bf(float f) {
    union { float f; unsigned int u; } c; c.f = f;
    unsigned int u = c.u;
    return (unsigned short)((u + 0x7FFFu + ((u >> 16) & 1u)) >> 16);
}
// window-order row (b, wi, wj, r, cc) -> pixel-order row (b, hp, wp).
// Same map for the LN1 gather (roll -4) and proj scatter (roll +4).
__device__ __forceinline__ int remap_row(int row) {
    int b  = row >> 12;
    int w6 = (row >> 6) & 63;
    int n  = row & 63;
    int hp = (((w6 >> 3) << 3) + (n >> 3) + 4) & 63;
    int wp = (((w6 & 7) << 3) + (n & 7) + 4) & 63;
    return (b << 12) | (hp << 6) | wp;
}
__device__ __forceinline__ float gelu_f(float v) {
    float c = v + 0.044715f * v * v * v;
    return 0.5f * v * (1.0f + tanhf(0.7978845608028654f * c));
}
__device__ __forceinline__ void gload16(const unsigned short* g, unsigned short* l) {
    __builtin_amdgcn_global_load_lds(
        (const __attribute__((address_space(1))) void*)g,
        (__attribute__((address_space(3))) void*)l, 16, 0, 0);
}

// ---- LayerNorm over C=256; one wave per row; optional gather remap --------
__global__ __launch_bounds__(256) void ln_kernel(
    const float* __restrict__ in, const float* __restrict__ g,
    const float* __restrict__ b, unsigned short* __restrict__ out, int remap)
{
    int wave = threadIdx.x >> 6, lane = threadIdx.x & 63;
    int row = (blockIdx.x << 2) + wave;
    int src = remap ? remap_row(row) : row;
    float4 xv = *(const float4*)(in + (size_t)src * 256 + (lane << 2));
    float s  = xv.x + xv.y + xv.z + xv.w;
    float ss = xv.x*xv.x + xv.y*xv.y + xv.z*xv.z + xv.w*xv.w;
#pragma unroll
    for (int off = 32; off; off >>= 1) {
        s  += __shfl_xor(s,  off, 64);
        ss += __shfl_xor(ss, off, 64);
    }
    float mu  = s * (1.0f / 256.0f);
    float inv = rsqrtf(ss * (1.0f / 256.0f) - mu * mu + 1e-5f);
    float4 gv = *(const float4*)(g + (lane << 2));
    float4 bv = *(const float4*)(b + (lane << 2));
    ushort4 o;
    o.x = f2bf((xv.x - mu) * inv * gv.x + bv.x);
    o.y = f2bf((xv.y - mu) * inv * gv.y + bv.y);
    o.z = f2bf((xv.z - mu) * inv * gv.z + bv.z);
    o.w = f2bf((xv.w - mu) * inv * gv.w + bv.w);
    *(ushort4*)(out + (size_t)row * 256 + (lane << 2)) = o;
}

// ---- expand rel-pos bias to [head][m][n] for coalesced attn reads ---------
__global__ __launch_bounds__(256) void bias_expand_kernel(
    const float* __restrict__ table, const int* __restrict__ relidx,
    float* __restrict__ out)
{
    int i = blockIdx.x * 256 + threadIdx.x;   // 8*64*64 = 32768
    int head = i >> 12;
    int m = (i >> 6) & 63;
    int n = i & 63;
    out[i] = table[relidx[n * 64 + m] * 8 + head];
}

// ---- weight convert: f32 [K,N] -> bf16 [N,K] (transposed) -----------------
__global__ __launch_bounds__(256) void convert_T_kernel(
    const float* __restrict__ in, unsigned short* __restrict__ out, int K, int N)
{
    __shared__ float t[32][33];
    int kb = K >> 5;
    int bk = (blockIdx.x % kb) << 5;
    int bn = (blockIdx.x / kb) << 5;
    int r = threadIdx.x >> 5, c = threadIdx.x & 31;
#pragma unroll
    for (int i = 0; i < 4; ++i)
        t[r + i * 8][c] = in[(size_t)(bk + r + i * 8) * N + bn + c];
    __syncthreads();
#pragma unroll
    for (int i = 0; i < 4; ++i)
        out[(size_t)(bn + r + i * 8) * K + bk + c] = f2bf(t[c][r + i * 8]);
}

// ---- MFMA GEMM: A bf16 [M,K] row-major, BT bf16 [N,K] row-major -----------
// 128x128 tile, BK=32, 4 waves (2x2), each wave 64x64 = 4x4 16x16x32 frags.
// OUT_BF16: write bf16; else f32 (+residual). DO_GELU: tanh-GELU epilogue.
// RESID: 0 none, 1 same-row residual, 2 scatter via remap_row + residual.
template<int OUT_BF16, int DO_GELU, int RESID>
__global__ __launch_bounds__(256) void mgemm_kernel(
    const unsigned short* __restrict__ A, const unsigned short* __restrict__ BT,
    const float* __restrict__ bias, void* __restrict__ outp,
    const float* __restrict__ resid, int M, int N, int K)
{
    __shared__ unsigned short As[128 * 32];
    __shared__ unsigned short Bs[128 * 32];

    const int nb = N >> 7;
    const int m0 = (int)(blockIdx.x / nb) << 7;
    const int n0 = (int)(blockIdx.x % nb) << 7;
    const int tid  = threadIdx.x;
    const int wid  = tid >> 6;
    const int lane = tid & 63;
    const int wm = (wid >> 1) << 6;       // wave row offset in tile
    const int wn = (wid & 1) << 6;        // wave col offset in tile

    const unsigned short* Ag = A  + (size_t)m0 * K;
    const unsigned short* Bg = BT + (size_t)n0 * K;
    const int s0 = tid, s1 = tid + 256;   // 16B staging slots (512 per matrix)

    f32x4 acc[4][4] = {};
    const int fr = lane & 15;             // row within 16x16 fragment
    const int fk = (lane >> 4) << 3;      // k offset (0,8,16,24) within BK=32

    for (int k0 = 0; k0 < K; k0 += 32) {
        gload16(Ag + (size_t)(s0 >> 2) * K + k0 + ((s0 & 3) << 3), As + s0 * 8);
        gload16(Ag + (size_t)(s1 >> 2) * K + k0 + ((s1 & 3) << 3), As + s1 * 8);
        gload16(Bg + (size_t)(s0 >> 2) * K + k0 + ((s0 & 3) << 3), Bs + s0 * 8);
        gload16(Bg + (size_t)(s1 >> 2) * K + k0 + ((s1 & 3) << 3), Bs + s1 * 8);
        __syncthreads();   // drains vmcnt(0): LDS staging complete

        bf16x8 af[4], bfr[4];
#pragma unroll
        for (int i = 0; i < 4; ++i)
            af[i] = *(const bf16x8*)(As + (wm + i * 16 + fr) * 32 + fk);
#pragma unroll
        for (int j = 0; j < 4; ++j)
            bfr[j] = *(const bf16x8*)(Bs + (wn + j * 16 + fr) * 32 + fk);
#pragma unroll
        for (int i = 0; i < 4; ++i)
#pragma unroll
            for (int j = 0; j < 4; ++j)
                acc[i][j] = __builtin_amdgcn_mfma_f32_16x16x32_bf16(
                    af[i], bfr[j], acc[i][j], 0, 0, 0);
        __syncthreads();
    }

#pragma unroll
    for (int i = 0; i < 4; ++i) {
#pragma unroll
        for (int j = 0; j < 4; ++j) {
            const int col = n0 + wn + j * 16 + (lane & 15);
            const float bv = bias[col];
#pragma unroll
            for (int v = 0; v < 4; ++v) {
                const int row = m0 + wm + i * 16 + ((lane >> 4) << 2) + v;
                float val = acc[i][j][v] + bv;
                if (DO_GELU) val = gelu_f(val);
                if (OUT_BF16) {
                    ((unsigned short*)outp)[(size_t)row * N + col] = f2bf(val);
                } else {
                    const int orow = (RESID == 2) ? remap_row(row) : row;
                    const float r = RESID ? resid[(size_t)orow * N + col] : 0.0f;
                    ((float*)outp)[(size_t)orow * N + col] = r + val;
                }
            }
        }
    }
}

// ---- window attention: one (window, head) per 64-thread block -------------
__global__ __launch_bounds__(64) void attn_kernel(
    const unsigned short* __restrict__ qkv,
    const float* __restrict__ biasT,       // [head][m][n]
    unsigned short* __restrict__ out)
{
    __shared__ float kt[64][32];
    __shared__ float vt[64][32];
    __shared__ int reg[64];
    const int widx = blockIdx.x >> 3;
    const int head = blockIdx.x & 7;
    const int n = threadIdx.x;

    {
        int w6 = widx & 63;
        int ph = ((w6 >> 3) << 3) + (n >> 3);
        int pw = ((w6 & 7) << 3) + (n & 7);
        int rh = (ph < 56) ? 0 : ((ph < 60) ? 1 : 2);
        int rw = (pw < 56) ? 0 : ((pw < 60) ? 1 : 2);
        reg[n] = rh * 3 + rw;
    }

    const size_t rowbase = ((size_t)widx * 64 + n) * 768 + head * 32;
    float q[32];
#pragma unroll
    for (int d = 0; d < 32; ++d) {
        q[d]     = bf2f(qkv[rowbase + d]) * 0.17677669529663687f;
        kt[n][d] = bf2f(qkv[rowbase + 256 + d]);
        vt[n][d] = bf2f(qkv[rowbase + 512 + d]);
    }
    __syncthreads();

    const float* bh = biasT + head * 4096 + n;
    const int myreg = reg[n];
    float s[64];
    float mx = -1e30f;
#pragma unroll
    for (int m = 0; m < 64; ++m) {
        float sum = 0.f;
#pragma unroll
        for (int d4 = 0; d4 < 8; ++d4) {
            float4 kv = *(const float4*)&kt[m][d4 << 2];
            sum += q[(d4 << 2) + 0] * kv.x + q[(d4 << 2) + 1] * kv.y
                 + q[(d4 << 2) + 2] * kv.z + q[(d4 << 2) + 3] * kv.w;
        }
        sum += bh[m * 64];
        if (myreg != reg[m]) sum -= 100.0f;
        s[m] = sum;
        mx = fmaxf(mx, sum);
    }
    float denom = 0.f;
#pragma unroll
    for (int m = 0; m < 64; ++m) { s[m] = __expf(s[m] - mx); denom += s[m]; }
    const float inv = 1.0f / denom;

    float o[32] = {};
#pragma unroll
    for (int m = 0; m < 64; ++m) {
        float p = s[m];
#pragma unroll
        for (int d4 = 0; d4 < 8; ++d4) {
            float4 vv = *(const float4*)&vt[m][d4 << 2];
            o[(d4 << 2) + 0] += p * vv.x;
            o[(d4 << 2) + 1] += p * vv.y;
            o[(d4 << 2) + 2] += p * vv.z;
            o[(d4 << 2) + 3] += p * vv.w;
        }
    }
    unsigned short* orow = out + ((size_t)widx * 64 + n) * 256 + head * 32;
#pragma unroll
    for (int d = 0; d < 32; ++d) orow[d] = f2bf(o[d] * inv);
}

// ---------------------------------------------------------------------------
extern "C" void kernel_launch(void* const* d_in, const int* in_sizes, int n_in,
                              void* d_out, int out_size, void* d_ws, size_t ws_size,
                              hipStream_t stream)
{
    const float* x      = (const float*)d_in[0];
    const float* ln1_g  = (const float*)d_in[1];
    const float* ln1_b  = (const float*)d_in[2];
    const float* qkv_w  = (const float*)d_in[3];
    const float* qkv_b  = (const float*)d_in[4];
    const float* proj_w = (const float*)d_in[5];
    const float* proj_b = (const float*)d_in[6];
    const float* table  = (const float*)d_in[7];
    const float* ln2_g  = (const float*)d_in[8];
    const float* ln2_b  = (const float*)d_in[9];
    const float* w1     = (const float*)d_in[10];
    const float* b1     = (const float*)d_in[11];
    const float* w2     = (const float*)d_in[12];
    const float* b2     = (const float*)d_in[13];
    const int*   relidx = (const int*)d_in[14];
    float* out = (float*)d_out;

    char* w = (char*)d_ws;
    unsigned short* xw   = (unsigned short*)w;                      // 32MB (xw -> attn_out -> ln2out)
    unsigned short* qkvb = (unsigned short*)(w + (32u << 20));      // 128MB (qkv 96MB -> mlp hidden 128MB)
    float*          h2   = (float*)(w + (160u << 20));              // 64MB
    float*          bexp = (float*)(w + (224u << 20));              // 128KB
    unsigned short* qkvT = (unsigned short*)(w + (224u << 20) + (128u << 10)); // 384KB
    unsigned short* prjT = qkvT + 768 * 256;                        // 128KB
    unsigned short* w1T  = prjT + 256 * 256;                        // 512KB
    unsigned short* w2T  = w1T + 1024 * 256;                        // 512KB

    // 0. weight transpose + bf16 convert
    convert_T_kernel<<<192, 256, 0, stream>>>(qkv_w, qkvT, 256, 768);
    convert_T_kernel<<< 64, 256, 0, stream>>>(proj_w, prjT, 256, 256);
    convert_T_kernel<<<256, 256, 0, stream>>>(w1, w1T, 256, 1024);
    convert_T_kernel<<<256, 256, 0, stream>>>(w2, w2T, 1024, 256);
    // 1. LN1 + cyclic shift + window partition (gather) -> xw bf16 [65536,256]
    ln_kernel<<<16384, 256, 0, stream>>>(x, ln1_g, ln1_b, xw, 1);
    // 1b. expand relative-position bias to [head][m][n]
    bias_expand_kernel<<<128, 256, 0, stream>>>(table, relidx, bexp);
    // 2. QKV GEMM -> qkvb bf16 [65536,768]
    mgemm_kernel<1, 0, 0><<<512 * 6, 256, 0, stream>>>(xw, qkvT, qkv_b, (void*)qkvb,
                                                       nullptr, 65536, 768, 256);
    // 3. window attention -> attn_out (reuse xw) bf16 [65536,256]
    attn_kernel<<<8192, 64, 0, stream>>>(qkvb, bexp, xw);
    // 4. proj GEMM + window-reverse/unshift scatter + residual(x) -> h2 f32
    mgemm_kernel<0, 0, 2><<<512 * 2, 256, 0, stream>>>(xw, prjT, proj_b, (void*)h2,
                                                       x, 65536, 256, 256);
    // 5. LN2 -> ln2out (reuse xw) bf16
    ln_kernel<<<16384, 256, 0, stream>>>(h2, ln2_g, ln2_b, xw, 0);
    // 6. MLP1 GEMM + GELU -> hidden (reuse qkvb) bf16 [65536,1024]
    mgemm_kernel<1, 1, 0><<<512 * 8, 256, 0, stream>>>(xw, w1T, b1, (void*)qkvb,
                                                       nullptr, 65536, 1024, 256);
    // 7. MLP2 GEMM + residual(h2) -> d_out f32
    mgemm_kernel<0, 0, 1><<<512 * 2, 256, 0, stream>>>(qkvb, w2T, b2, (void*)out,
                                                       h2, 65536, 256, 1024);
}

// Round 3
// 368.588 us; speedup vs baseline: 4.1777x; 1.4898x over previous
//
#include <hip/hip_runtime.h>

// ---------------------------------------------------------------------------
// Swin block: LN1 -> shift+window -> QKV -> win-attn(+relbias+mask) -> proj
//             -> reverse+residual -> LN2 -> MLP(GELU) -> residual
// B=16 H=W=64 C=256 WS=8 SHIFT=4 HEADS=8 HD=32 N=64 HID=1024
// Round 2: attention -> MFMA 32x32x16 (swapped QK^T, in-register softmax,
//          cvt_pk+permlane32_swap P-frag build, V^T in swizzled LDS).
//          Q pre-scaled by hd^-0.5 in QKV GEMM epilogue. Same-XCD head blocks.
// ---------------------------------------------------------------------------

typedef __attribute__((ext_vector_type(8))) short bf16x8;
typedef __attribute__((ext_vector_type(4))) float f32x4;
typedef __attribute__((ext_vector_type(16))) float f32x16;

__device__ __forceinline__ float bf2f(unsigned short h) {
    union { unsigned int u; float f; } c; c.u = ((unsigned int)h) << 16; return c.f;
}
__device__ __forceinline__ unsigned short f2bf(float f) {
    union { float f; unsigned int u; } c; c.f = f;
    unsigned int u = c.u;
    return (unsigned short)((u + 0x7FFFu + ((u >> 16) & 1u)) >> 16);
}
__device__ __forceinline__ unsigned int cvtpk_bf16(float lo, float hi) {
    unsigned int r;
    asm volatile("v_cvt_pk_bf16_f32 %0, %1, %2" : "=v"(r) : "v"(lo), "v"(hi));
    return r;
}
// v_permlane32_swap_b32: a.upper32lanes <-> b.lower32lanes (both modified)
__device__ __forceinline__ void perm32swap(unsigned int& a, unsigned int& b) {
    asm volatile("v_permlane32_swap_b32 %0, %1" : "+v"(a), "+v"(b));
}
// window-order row (b, wi, wj, r, cc) -> pixel-order row (b, hp, wp).
__device__ __forceinline__ int remap_row(int row) {
    int b  = row >> 12;
    int w6 = (row >> 6) & 63;
    int n  = row & 63;
    int hp = (((w6 >> 3) << 3) + (n >> 3) + 4) & 63;
    int wp = (((w6 & 7) << 3) + (n & 7) + 4) & 63;
    return (b << 12) | (hp << 6) | wp;
}
__device__ __forceinline__ float gelu_f(float v) {
    float c = v + 0.044715f * v * v * v;
    return 0.5f * v * (1.0f + tanhf(0.7978845608028654f * c));
}
__device__ __forceinline__ void gload16(const unsigned short* g, unsigned short* l) {
    __builtin_amdgcn_global_load_lds(
        (const __attribute__((address_space(1))) void*)g,
        (__attribute__((address_space(3))) void*)l, 16, 0, 0);
}

// ---- LayerNorm over C=256; one wave per row; optional gather remap --------
__global__ __launch_bounds__(256) void ln_kernel(
    const float* __restrict__ in, const float* __restrict__ g,
    const float* __restrict__ b, unsigned short* __restrict__ out, int remap)
{
    int wave = threadIdx.x >> 6, lane = threadIdx.x & 63;
    int row = (blockIdx.x << 2) + wave;
    int src = remap ? remap_row(row) : row;
    float4 xv = *(const float4*)(in + (size_t)src * 256 + (lane << 2));
    float s  = xv.x + xv.y + xv.z + xv.w;
    float ss = xv.x*xv.x + xv.y*xv.y + xv.z*xv.z + xv.w*xv.w;
#pragma unroll
    for (int off = 32; off; off >>= 1) {
        s  += __shfl_xor(s,  off, 64);
        ss += __shfl_xor(ss, off, 64);
    }
    float mu  = s * (1.0f / 256.0f);
    float inv = rsqrtf(ss * (1.0f / 256.0f) - mu * mu + 1e-5f);
    float4 gv = *(const float4*)(g + (lane << 2));
    float4 bv = *(const float4*)(b + (lane << 2));
    ushort4 o;
    o.x = f2bf((xv.x - mu) * inv * gv.x + bv.x);
    o.y = f2bf((xv.y - mu) * inv * gv.y + bv.y);
    o.z = f2bf((xv.z - mu) * inv * gv.z + bv.z);
    o.w = f2bf((xv.w - mu) * inv * gv.w + bv.w);
    *(ushort4*)(out + (size_t)row * 256 + (lane << 2)) = o;
}

// ---- expand rel-pos bias to [head][q][key] f32 -----------------------------
__global__ __launch_bounds__(256) void bias_expand_kernel(
    const float* __restrict__ table, const int* __restrict__ relidx,
    float* __restrict__ out)
{
    int i = blockIdx.x * 256 + threadIdx.x;   // 8*64*64 = 32768
    int head = i >> 12;
    int q = (i >> 6) & 63;
    int k = i & 63;
    out[i] = table[relidx[q * 64 + k] * 8 + head];
}

// ---- weight convert: f32 [K,N] -> bf16 [N,K] (transposed) -----------------
__global__ __launch_bounds__(256) void convert_T_kernel(
    const float* __restrict__ in, unsigned short* __restrict__ out, int K, int N)
{
    __shared__ float t[32][33];
    int kb = K >> 5;
    int bk = (blockIdx.x % kb) << 5;
    int bn = (blockIdx.x / kb) << 5;
    int r = threadIdx.x >> 5, c = threadIdx.x & 31;
#pragma unroll
    for (int i = 0; i < 4; ++i)
        t[r + i * 8][c] = in[(size_t)(bk + r + i * 8) * N + bn + c];
    __syncthreads();
#pragma unroll
    for (int i = 0; i < 4; ++i)
        out[(size_t)(bn + r + i * 8) * K + bk + c] = f2bf(t[c][r + i * 8]);
}

// ---- MFMA GEMM: A bf16 [M,K] row-major, BT bf16 [N,K] row-major -----------
// 128x128 tile, BK=32, 4 waves (2x2), each wave 64x64 = 4x4 16x16x32 frags.
template<int OUT_BF16, int DO_GELU, int RESID, int QSCALE>
__global__ __launch_bounds__(256) void mgemm_kernel(
    const unsigned short* __restrict__ A, const unsigned short* __restrict__ BT,
    const float* __restrict__ bias, void* __restrict__ outp,
    const float* __restrict__ resid, int M, int N, int K)
{
    __shared__ unsigned short As[128 * 32];
    __shared__ unsigned short Bs[128 * 32];

    const int nb = N >> 7;
    const int m0 = (int)(blockIdx.x / nb) << 7;
    const int n0 = (int)(blockIdx.x % nb) << 7;
    const int tid  = threadIdx.x;
    const int wid  = tid >> 6;
    const int lane = tid & 63;
    const int wm = (wid >> 1) << 6;
    const int wn = (wid & 1) << 6;

    const unsigned short* Ag = A  + (size_t)m0 * K;
    const unsigned short* Bg = BT + (size_t)n0 * K;
    const int s0 = tid, s1 = tid + 256;

    f32x4 acc[4][4] = {};
    const int fr = lane & 15;
    const int fk = (lane >> 4) << 3;

    for (int k0 = 0; k0 < K; k0 += 32) {
        gload16(Ag + (size_t)(s0 >> 2) * K + k0 + ((s0 & 3) << 3), As + s0 * 8);
        gload16(Ag + (size_t)(s1 >> 2) * K + k0 + ((s1 & 3) << 3), As + s1 * 8);
        gload16(Bg + (size_t)(s0 >> 2) * K + k0 + ((s0 & 3) << 3), Bs + s0 * 8);
        gload16(Bg + (size_t)(s1 >> 2) * K + k0 + ((s1 & 3) << 3), Bs + s1 * 8);
        __syncthreads();

        bf16x8 af[4], bfr[4];
#pragma unroll
        for (int i = 0; i < 4; ++i)
            af[i] = *(const bf16x8*)(As + (wm + i * 16 + fr) * 32 + fk);
#pragma unroll
        for (int j = 0; j < 4; ++j)
            bfr[j] = *(const bf16x8*)(Bs + (wn + j * 16 + fr) * 32 + fk);
#pragma unroll
        for (int i = 0; i < 4; ++i)
#pragma unroll
            for (int j = 0; j < 4; ++j)
                acc[i][j] = __builtin_amdgcn_mfma_f32_16x16x32_bf16(
                    af[i], bfr[j], acc[i][j], 0, 0, 0);
        __syncthreads();
    }

#pragma unroll
    for (int i = 0; i < 4; ++i) {
#pragma unroll
        for (int j = 0; j < 4; ++j) {
            const int col = n0 + wn + j * 16 + (lane & 15);
            const float bv = bias[col];
#pragma unroll
            for (int v = 0; v < 4; ++v) {
                const int row = m0 + wm + i * 16 + ((lane >> 4) << 2) + v;
                float val = acc[i][j][v] + bv;
                if (QSCALE) { if (col < 256) val *= 0.17677669529663687f; }
                if (DO_GELU) val = gelu_f(val);
                if (OUT_BF16) {
                    ((unsigned short*)outp)[(size_t)row * N + col] = f2bf(val);
                } else {
                    const int orow = (RESID == 2) ? remap_row(row) : row;
                    const float r = RESID ? resid[(size_t)orow * N + col] : 0.0f;
                    ((float*)outp)[(size_t)orow * N + col] = r + val;
                }
            }
        }
    }
}

// ---- MFMA window attention: one wave per (window, head) -------------------
// qkv bf16 [65536,768] (q|k|v, head*32+d within each; q pre-scaled).
// S^T = mfma32x32x16(K, Q): lane holds col q=l&31, rows key=crow(r,hi).
// out bf16 [65536,256].
__global__ __launch_bounds__(64, 3) void attn_kernel(
    const unsigned short* __restrict__ qkv,
    const float* __restrict__ bexp,        // [head][q][key] f32
    unsigned short* __restrict__ out)
{
    __shared__ unsigned short VT[2048];    // V^T [32 d][64 key], XOR-swizzled
    const int bid  = blockIdx.x;
    const int widx = bid & 1023;           // consecutive bids share XCD per window-set
    const int head = bid >> 10;
    const int l  = threadIdx.x;
    const int lo = l & 31, hi = l >> 5;

    const unsigned short* base = qkv + (size_t)widx * 64 * 768;

    // ---- stage V^T (lane = key row); swizzle ^((d&7)<<4) --------------------
#pragma unroll
    for (int c = 0; c < 4; ++c) {
        union { bf16x8 v; unsigned short s[8]; } u;
        u.v = *(const bf16x8*)(base + (size_t)l * 768 + 512 + head * 32 + c * 8);
#pragma unroll
        for (int e = 0; e < 8; ++e) {
            int d = c * 8 + e;
            int wb = ((d * 64 + l) * 2) ^ ((d & 7) << 4);
            *(unsigned short*)((char*)VT + wb) = u.s[e];
        }
    }

    // ---- S^T = K · Q^T (8 MFMA) ---------------------------------------------
    f32x16 acc[2][2] = {};   // [kb][qb]
#pragma unroll
    for (int kd = 0; kd < 2; ++kd) {
        const int coff = head * 32 + kd * 16 + hi * 8;
        bf16x8 kf0 = *(const bf16x8*)(base + (size_t)lo        * 768 + 256 + coff);
        bf16x8 kf1 = *(const bf16x8*)(base + (size_t)(32 + lo) * 768 + 256 + coff);
        bf16x8 qf0 = *(const bf16x8*)(base + (size_t)lo        * 768 + coff);
        bf16x8 qf1 = *(const bf16x8*)(base + (size_t)(32 + lo) * 768 + coff);
        acc[0][0] = __builtin_amdgcn_mfma_f32_32x32x16_bf16(kf0, qf0, acc[0][0], 0, 0, 0);
        acc[0][1] = __builtin_amdgcn_mfma_f32_32x32x16_bf16(kf0, qf1, acc[0][1], 0, 0, 0);
        acc[1][0] = __builtin_amdgcn_mfma_f32_32x32x16_bf16(kf1, qf0, acc[1][0], 0, 0, 0);
        acc[1][1] = __builtin_amdgcn_mfma_f32_32x32x16_bf16(kf1, qf1, acc[1][1], 0, 0, 0);
    }

    // ---- + relative-position bias -------------------------------------------
#pragma unroll
    for (int qb = 0; qb < 2; ++qb) {
        const float* bq = bexp + head * 4096 + (qb * 32 + lo) * 64;
#pragma unroll
        for (int kb = 0; kb < 2; ++kb)
#pragma unroll
            for (int j = 0; j < 4; ++j) {
                float4 b4 = *(const float4*)(bq + kb * 32 + j * 8 + hi * 4);
                acc[kb][qb][4 * j + 0] += b4.x;
                acc[kb][qb][4 * j + 1] += b4.y;
                acc[kb][qb][4 * j + 2] += b4.z;
                acc[kb][qb][4 * j + 3] += b4.w;
            }
    }

    // ---- shifted-window mask (edge windows only; block-uniform branch) ------
    const int w6 = widx & 63;
    if (((w6 >> 3) == 7) || ((w6 & 7) == 7)) {
#pragma unroll
        for (int qb = 0; qb < 2; ++qb) {
            int nq = qb * 32 + lo;
            int phq = ((w6 >> 3) << 3) + (nq >> 3), pwq = ((w6 & 7) << 3) + (nq & 7);
            int rq = ((phq < 56) ? 0 : ((phq < 60) ? 1 : 2)) * 3
                   + ((pwq < 56) ? 0 : ((pwq < 60) ? 1 : 2));
#pragma unroll
            for (int kb = 0; kb < 2; ++kb)
#pragma unroll
                for (int r = 0; r < 16; ++r) {
                    int nk = kb * 32 + (r & 3) + 8 * (r >> 2) + 4 * hi;
                    int phk = ((w6 >> 3) << 3) + (nk >> 3), pwk = ((w6 & 7) << 3) + (nk & 7);
                    int rk = ((phk < 56) ? 0 : ((phk < 60) ? 1 : 2)) * 3
                           + ((pwk < 56) ? 0 : ((pwk < 60) ? 1 : 2));
                    if (rk != rq) acc[kb][qb][r] -= 100.0f;
                }
        }
    }

    // ---- softmax (per q = col l&31; partner lane l^32 has other 32 keys) ----
#pragma unroll
    for (int qb = 0; qb < 2; ++qb) {
        float mx = acc[0][qb][0];
#pragma unroll
        for (int r = 1; r < 16; ++r) mx = fmaxf(mx, acc[0][qb][r]);
#pragma unroll
        for (int r = 0; r < 16; ++r) mx = fmaxf(mx, acc[1][qb][r]);
        mx = fmaxf(mx, __shfl_xor(mx, 32, 64));
        float sum = 0.f;
#pragma unroll
        for (int kb = 0; kb < 2; ++kb)
#pragma unroll
            for (int r = 0; r < 16; ++r) {
                float e = __expf(acc[kb][qb][r] - mx);
                acc[kb][qb][r] = e;
                sum += e;
            }
        sum += __shfl_xor(sum, 32, 64);
        float inv = 1.0f / sum;
#pragma unroll
        for (int kb = 0; kb < 2; ++kb)
#pragma unroll
            for (int r = 0; r < 16; ++r) acc[kb][qb][r] *= inv;
    }

    // ---- O = P · V (8 MFMA); P-frags via cvt_pk + permlane32_swap -----------
    f32x16 o[2] = {};
#pragma unroll
    for (int ks = 0; ks < 4; ++ks) {
        const int s8 = (ks & 1) * 8, kb = ks >> 1;
        const int rb = ((lo * 64 + 16 * ks + 8 * hi) * 2) ^ ((lo & 7) << 4);
        bf16x8 vb = *(const bf16x8*)((const char*)VT + rb);
#pragma unroll
        for (int qb = 0; qb < 2; ++qb) {
            unsigned int a0 = cvtpk_bf16(acc[kb][qb][s8 + 0], acc[kb][qb][s8 + 1]);
            unsigned int b0 = cvtpk_bf16(acc[kb][qb][s8 + 4], acc[kb][qb][s8 + 5]);
            unsigned int a1 = cvtpk_bf16(acc[kb][qb][s8 + 2], acc[kb][qb][s8 + 3]);
            unsigned int b1 = cvtpk_bf16(acc[kb][qb][s8 + 6], acc[kb][qb][s8 + 7]);
            perm32swap(a0, b0);
            perm32swap(a1, b1);
            union { unsigned int u[4]; bf16x8 v; } w;
            w.u[0] = a0; w.u[1] = a1; w.u[2] = b0; w.u[3] = b1;
            o[qb] = __builtin_amdgcn_mfma_f32_32x32x16_bf16(w.v, vb, o[qb], 0, 0, 0);
        }
    }

    // ---- write O[q, d=lo] bf16 ----------------------------------------------
    unsigned short* ob = out + (size_t)widx * 64 * 256 + head * 32 + lo;
#pragma unroll
    for (int qb = 0; qb < 2; ++qb)
#pragma unroll
        for (int r = 0; r < 16; ++r) {
            int q = qb * 32 + (r & 3) + 8 * (r >> 2) + 4 * hi;
            ob[(size_t)q * 256] = f2bf(o[qb][r]);
        }
}

// ---------------------------------------------------------------------------
extern "C" void kernel_launch(void* const* d_in, const int* in_sizes, int n_in,
                              void* d_out, int out_size, void* d_ws, size_t ws_size,
                              hipStream_t stream)
{
    const float* x      = (const float*)d_in[0];
    const float* ln1_g  = (const float*)d_in[1];
    const float* ln1_b  = (const float*)d_in[2];
    const float* qkv_w  = (const float*)d_in[3];
    const float* qkv_b  = (const float*)d_in[4];
    const float* proj_w = (const float*)d_in[5];
    const float* proj_b = (const float*)d_in[6];
    const float* table  = (const float*)d_in[7];
    const float* ln2_g  = (const float*)d_in[8];
    const float* ln2_b  = (const float*)d_in[9];
    const float* w1     = (const float*)d_in[10];
    const float* b1     = (const float*)d_in[11];
    const float* w2     = (const float*)d_in[12];
    const float* b2     = (const float*)d_in[13];
    const int*   relidx = (const int*)d_in[14];
    float* out = (float*)d_out;

    char* w = (char*)d_ws;
    unsigned short* xw   = (unsigned short*)w;                      // 32MB (xw -> attn_out -> ln2out)
    unsigned short* qkvb = (unsigned short*)(w + (32u << 20));      // 128MB (qkv 96MB -> mlp hidden 128MB)
    float*          h2   = (float*)(w + (160u << 20));              // 64MB
    float*          bexp = (float*)(w + (224u << 20));              // 128KB
    unsigned short* qkvT = (unsigned short*)(w + (224u << 20) + (128u << 10)); // 384KB
    unsigned short* prjT = qkvT + 768 * 256;                        // 128KB
    unsigned short* w1T  = prjT + 256 * 256;                        // 512KB
    unsigned short* w2T  = w1T + 1024 * 256;                        // 512KB

    // 0. weight transpose + bf16 convert
    convert_T_kernel<<<192, 256, 0, stream>>>(qkv_w, qkvT, 256, 768);
    convert_T_kernel<<< 64, 256, 0, stream>>>(proj_w, prjT, 256, 256);
    convert_T_kernel<<<256, 256, 0, stream>>>(w1, w1T, 256, 1024);
    convert_T_kernel<<<256, 256, 0, stream>>>(w2, w2T, 1024, 256);
    // 1. LN1 + cyclic shift + window partition (gather) -> xw bf16 [65536,256]
    ln_kernel<<<16384, 256, 0, stream>>>(x, ln1_g, ln1_b, xw, 1);
    // 1b. expand relative-position bias to [head][q][key]
    bias_expand_kernel<<<128, 256, 0, stream>>>(table, relidx, bexp);
    // 2. QKV GEMM (q cols pre-scaled by hd^-0.5) -> qkvb bf16 [65536,768]
    mgemm_kernel<1, 0, 0, 1><<<512 * 6, 256, 0, stream>>>(xw, qkvT, qkv_b, (void*)qkvb,
                                                          nullptr, 65536, 768, 256);
    // 3. MFMA window attention -> attn_out (reuse xw) bf16 [65536,256]
    attn_kernel<<<8192, 64, 0, stream>>>(qkvb, bexp, xw);
    // 4. proj GEMM + window-reverse/unshift scatter + residual(x) -> h2 f32
    mgemm_kernel<0, 0, 2, 0><<<512 * 2, 256, 0, stream>>>(xw, prjT, proj_b, (void*)h2,
                                                          x, 65536, 256, 256);
    // 5. LN2 -> ln2out (reuse xw) bf16
    ln_kernel<<<16384, 256, 0, stream>>>(h2, ln2_g, ln2_b, xw, 0);
    // 6. MLP1 GEMM + GELU -> hidden (reuse qkvb) bf16 [65536,1024]
    mgemm_kernel<1, 1, 0, 0><<<512 * 8, 256, 0, stream>>>(xw, w1T, b1, (void*)qkvb,
                                                          nullptr, 65536, 1024, 256);
    // 7. MLP2 GEMM + residual(h2) -> d_out f32
    mgemm_kernel<0, 0, 1, 0><<<512 * 2, 256, 0, stream>>>(qkvb, w2T, b2, (void*)out,
                                                          h2, 65536, 256, 1024);
}

// Round 4
// 323.475 us; speedup vs baseline: 4.7603x; 1.1395x over previous
//
#include <hip/hip_runtime.h>

// ---------------------------------------------------------------------------
// Swin block: LN1 -> shift+window -> QKV -> win-attn(+relbias+mask) -> proj
//             -> reverse+residual -> LN2 -> MLP(GELU) -> residual
// B=16 H=W=64 C=256 WS=8 SHIFT=4 HEADS=8 HD=32 N=64 HID=1024
// Round 3: mgemm gets (1) sigmoid-form fast GELU (no tanhf), (2) 2-phase
//          double-buffered global_load_lds prefetch, (3) bijective XCD swizzle
//          so A-panel-sharing blocks land on one XCD's L2.
// ---------------------------------------------------------------------------

typedef __attribute__((ext_vector_type(8))) short bf16x8;
typedef __attribute__((ext_vector_type(4))) float f32x4;
typedef __attribute__((ext_vector_type(16))) float f32x16;

__device__ __forceinline__ float bf2f(unsigned short h) {
    union { unsigned int u; float f; } c; c.u = ((unsigned int)h) << 16; return c.f;
}
__device__ __forceinline__ unsigned short f2bf(float f) {
    union { float f; unsigned int u; } c; c.f = f;
    unsigned int u = c.u;
    return (unsigned short)((u + 0x7FFFu + ((u >> 16) & 1u)) >> 16);
}
__device__ __forceinline__ unsigned int cvtpk_bf16(float lo, float hi) {
    unsigned int r;
    asm volatile("v_cvt_pk_bf16_f32 %0, %1, %2" : "=v"(r) : "v"(lo), "v"(hi));
    return r;
}
__device__ __forceinline__ void perm32swap(unsigned int& a, unsigned int& b) {
    asm volatile("v_permlane32_swap_b32 %0, %1" : "+v"(a), "+v"(b));
}
// window-order row (b, wi, wj, r, cc) -> pixel-order row (b, hp, wp).
__device__ __forceinline__ int remap_row(int row) {
    int b  = row >> 12;
    int w6 = (row >> 6) & 63;
    int n  = row & 63;
    int hp = (((w6 >> 3) << 3) + (n >> 3) + 4) & 63;
    int wp = (((w6 & 7) << 3) + (n & 7) + 4) & 63;
    return (b << 12) | (hp << 6) | wp;
}
// gelu(v) = v * sigmoid(2c(v + 0.044715 v^3)), c = sqrt(2/pi)
__device__ __forceinline__ float gelu_f(float v) {
    float u = 1.5957691216057308f * (v + 0.044715f * v * v * v);
    return v / (1.0f + __expf(-u));
}
__device__ __forceinline__ void gload16(const unsigned short* g, unsigned short* l) {
    __builtin_amdgcn_global_load_lds(
        (const __attribute__((address_space(1))) void*)g,
        (__attribute__((address_space(3))) void*)l, 16, 0, 0);
}

// ---- LayerNorm over C=256; one wave per row; optional gather remap --------
__global__ __launch_bounds__(256) void ln_kernel(
    const float* __restrict__ in, const float* __restrict__ g,
    const float* __restrict__ b, unsigned short* __restrict__ out, int remap)
{
    int wave = threadIdx.x >> 6, lane = threadIdx.x & 63;
    int row = (blockIdx.x << 2) + wave;
    int src = remap ? remap_row(row) : row;
    float4 xv = *(const float4*)(in + (size_t)src * 256 + (lane << 2));
    float s  = xv.x + xv.y + xv.z + xv.w;
    float ss = xv.x*xv.x + xv.y*xv.y + xv.z*xv.z + xv.w*xv.w;
#pragma unroll
    for (int off = 32; off; off >>= 1) {
        s  += __shfl_xor(s,  off, 64);
        ss += __shfl_xor(ss, off, 64);
    }
    float mu  = s * (1.0f / 256.0f);
    float inv = rsqrtf(ss * (1.0f / 256.0f) - mu * mu + 1e-5f);
    float4 gv = *(const float4*)(g + (lane << 2));
    float4 bv = *(const float4*)(b + (lane << 2));
    ushort4 o;
    o.x = f2bf((xv.x - mu) * inv * gv.x + bv.x);
    o.y = f2bf((xv.y - mu) * inv * gv.y + bv.y);
    o.z = f2bf((xv.z - mu) * inv * gv.z + bv.z);
    o.w = f2bf((xv.w - mu) * inv * gv.w + bv.w);
    *(ushort4*)(out + (size_t)row * 256 + (lane << 2)) = o;
}

// ---- expand rel-pos bias to [head][q][key] f32 -----------------------------
__global__ __launch_bounds__(256) void bias_expand_kernel(
    const float* __restrict__ table, const int* __restrict__ relidx,
    float* __restrict__ out)
{
    int i = blockIdx.x * 256 + threadIdx.x;   // 8*64*64 = 32768
    int head = i >> 12;
    int q = (i >> 6) & 63;
    int k = i & 63;
    out[i] = table[relidx[q * 64 + k] * 8 + head];
}

// ---- weight convert: f32 [K,N] -> bf16 [N,K] (transposed) -----------------
__global__ __launch_bounds__(256) void convert_T_kernel(
    const float* __restrict__ in, unsigned short* __restrict__ out, int K, int N)
{
    __shared__ float t[32][33];
    int kb = K >> 5;
    int bk = (blockIdx.x % kb) << 5;
    int bn = (blockIdx.x / kb) << 5;
    int r = threadIdx.x >> 5, c = threadIdx.x & 31;
#pragma unroll
    for (int i = 0; i < 4; ++i)
        t[r + i * 8][c] = in[(size_t)(bk + r + i * 8) * N + bn + c];
    __syncthreads();
#pragma unroll
    for (int i = 0; i < 4; ++i)
        out[(size_t)(bn + r + i * 8) * K + bk + c] = f2bf(t[c][r + i * 8]);
}

// ---- MFMA GEMM: A bf16 [M,K] row-major, BT bf16 [N,K] row-major -----------
// 128x128 tile, BK=32, 4 waves (2x2), each wave 64x64 = 4x4 16x16x32 frags.
// 2-phase double-buffered global_load_lds prefetch; XCD-swizzled blockIdx.
template<int OUT_BF16, int DO_GELU, int RESID, int QSCALE>
__global__ __launch_bounds__(256) void mgemm_kernel(
    const unsigned short* __restrict__ A, const unsigned short* __restrict__ BT,
    const float* __restrict__ bias, void* __restrict__ outp,
    const float* __restrict__ resid, int M, int N, int K)
{
    __shared__ unsigned short As[2][128 * 32];
    __shared__ unsigned short Bs[2][128 * 32];

    // T1 XCD swizzle (grid always a multiple of 8): XCD x gets a contiguous
    // chunk of logical block space -> A-panel-sharing blocks hit one L2.
    const int cpx = (int)gridDim.x >> 3;
    const int bid = ((int)blockIdx.x & 7) * cpx + ((int)blockIdx.x >> 3);

    const int nb = N >> 7;
    const int m0 = (bid / nb) << 7;
    const int n0 = (bid % nb) << 7;
    const int tid  = threadIdx.x;
    const int wid  = tid >> 6;
    const int lane = tid & 63;
    const int wm = (wid >> 1) << 6;
    const int wn = (wid & 1) << 6;

    const unsigned short* Ag = A  + (size_t)m0 * K;
    const unsigned short* Bg = BT + (size_t)n0 * K;
    const int s0 = tid, s1 = tid + 256;
    const size_t ra0 = (size_t)(s0 >> 2) * K + ((s0 & 3) << 3);
    const size_t ra1 = (size_t)(s1 >> 2) * K + ((s1 & 3) << 3);

    f32x4 acc[4][4] = {};
    const int fr = lane & 15;
    const int fk = (lane >> 4) << 3;

    // prologue: stage k0=0 into buf 0
    gload16(Ag + ra0, As[0] + s0 * 8);
    gload16(Ag + ra1, As[0] + s1 * 8);
    gload16(Bg + ra0, Bs[0] + s0 * 8);
    gload16(Bg + ra1, Bs[0] + s1 * 8);
    __syncthreads();

    int cur = 0;
    for (int k0 = 0; k0 < K; k0 += 32) {
        // prefetch next tile into the other buffer (loads in flight during MFMA)
        if (k0 + 32 < K) {
            const int nxt = cur ^ 1;
            gload16(Ag + ra0 + k0 + 32, As[nxt] + s0 * 8);
            gload16(Ag + ra1 + k0 + 32, As[nxt] + s1 * 8);
            gload16(Bg + ra0 + k0 + 32, Bs[nxt] + s0 * 8);
            gload16(Bg + ra1 + k0 + 32, Bs[nxt] + s1 * 8);
        }

        bf16x8 af[4], bfr[4];
#pragma unroll
        for (int i = 0; i < 4; ++i)
            af[i] = *(const bf16x8*)(As[cur] + (wm + i * 16 + fr) * 32 + fk);
#pragma unroll
        for (int j = 0; j < 4; ++j)
            bfr[j] = *(const bf16x8*)(Bs[cur] + (wn + j * 16 + fr) * 32 + fk);
#pragma unroll
        for (int i = 0; i < 4; ++i)
#pragma unroll
            for (int j = 0; j < 4; ++j)
                acc[i][j] = __builtin_amdgcn_mfma_f32_16x16x32_bf16(
                    af[i], bfr[j], acc[i][j], 0, 0, 0);
        __syncthreads();   // drains vmcnt(0) (prefetch done) + lgkm (reads done)
        cur ^= 1;
    }

#pragma unroll
    for (int i = 0; i < 4; ++i) {
#pragma unroll
        for (int j = 0; j < 4; ++j) {
            const int col = n0 + wn + j * 16 + (lane & 15);
            const float bv = bias[col];
#pragma unroll
            for (int v = 0; v < 4; ++v) {
                const int row = m0 + wm + i * 16 + ((lane >> 4) << 2) + v;
                float val = acc[i][j][v] + bv;
                if (QSCALE) { if (col < 256) val *= 0.17677669529663687f; }
                if (DO_GELU) val = gelu_f(val);
                if (OUT_BF16) {
                    ((unsigned short*)outp)[(size_t)row * N + col] = f2bf(val);
                } else {
                    const int orow = (RESID == 2) ? remap_row(row) : row;
                    const float r = RESID ? resid[(size_t)orow * N + col] : 0.0f;
                    ((float*)outp)[(size_t)orow * N + col] = r + val;
                }
            }
        }
    }
}

// ---- MFMA window attention: one wave per (window, head) -------------------
__global__ __launch_bounds__(64, 3) void attn_kernel(
    const unsigned short* __restrict__ qkv,
    const float* __restrict__ bexp,        // [head][q][key] f32
    unsigned short* __restrict__ out)
{
    __shared__ unsigned short VT[2048];    // V^T [32 d][64 key], XOR-swizzled
    const int bid  = blockIdx.x;
    const int widx = bid & 1023;
    const int head = bid >> 10;
    const int l  = threadIdx.x;
    const int lo = l & 31, hi = l >> 5;

    const unsigned short* base = qkv + (size_t)widx * 64 * 768;

#pragma unroll
    for (int c = 0; c < 4; ++c) {
        union { bf16x8 v; unsigned short s[8]; } u;
        u.v = *(const bf16x8*)(base + (size_t)l * 768 + 512 + head * 32 + c * 8);
#pragma unroll
        for (int e = 0; e < 8; ++e) {
            int d = c * 8 + e;
            int wb = ((d * 64 + l) * 2) ^ ((d & 7) << 4);
            *(unsigned short*)((char*)VT + wb) = u.s[e];
        }
    }

    f32x16 acc[2][2] = {};   // [kb][qb]
#pragma unroll
    for (int kd = 0; kd < 2; ++kd) {
        const int coff = head * 32 + kd * 16 + hi * 8;
        bf16x8 kf0 = *(const bf16x8*)(base + (size_t)lo        * 768 + 256 + coff);
        bf16x8 kf1 = *(const bf16x8*)(base + (size_t)(32 + lo) * 768 + 256 + coff);
        bf16x8 qf0 = *(const bf16x8*)(base + (size_t)lo        * 768 + coff);
        bf16x8 qf1 = *(const bf16x8*)(base + (size_t)(32 + lo) * 768 + coff);
        acc[0][0] = __builtin_amdgcn_mfma_f32_32x32x16_bf16(kf0, qf0, acc[0][0], 0, 0, 0);
        acc[0][1] = __builtin_amdgcn_mfma_f32_32x32x16_bf16(kf0, qf1, acc[0][1], 0, 0, 0);
        acc[1][0] = __builtin_amdgcn_mfma_f32_32x32x16_bf16(kf1, qf0, acc[1][0], 0, 0, 0);
        acc[1][1] = __builtin_amdgcn_mfma_f32_32x32x16_bf16(kf1, qf1, acc[1][1], 0, 0, 0);
    }

#pragma unroll
    for (int qb = 0; qb < 2; ++qb) {
        const float* bq = bexp + head * 4096 + (qb * 32 + lo) * 64;
#pragma unroll
        for (int kb = 0; kb < 2; ++kb)
#pragma unroll
            for (int j = 0; j < 4; ++j) {
                float4 b4 = *(const float4*)(bq + kb * 32 + j * 8 + hi * 4);
                acc[kb][qb][4 * j + 0] += b4.x;
                acc[kb][qb][4 * j + 1] += b4.y;
                acc[kb][qb][4 * j + 2] += b4.z;
                acc[kb][qb][4 * j + 3] += b4.w;
            }
    }

    const int w6 = widx & 63;
    if (((w6 >> 3) == 7) || ((w6 & 7) == 7)) {
#pragma unroll
        for (int qb = 0; qb < 2; ++qb) {
            int nq = qb * 32 + lo;
            int phq = ((w6 >> 3) << 3) + (nq >> 3), pwq = ((w6 & 7) << 3) + (nq & 7);
            int rq = ((phq < 56) ? 0 : ((phq < 60) ? 1 : 2)) * 3
                   + ((pwq < 56) ? 0 : ((pwq < 60) ? 1 : 2));
#pragma unroll
            for (int kb = 0; kb < 2; ++kb)
#pragma unroll
                for (int r = 0; r < 16; ++r) {
                    int nk = kb * 32 + (r & 3) + 8 * (r >> 2) + 4 * hi;
                    int phk = ((w6 >> 3) << 3) + (nk >> 3), pwk = ((w6 & 7) << 3) + (nk & 7);
                    int rk = ((phk < 56) ? 0 : ((phk < 60) ? 1 : 2)) * 3
                           + ((pwk < 56) ? 0 : ((pwk < 60) ? 1 : 2));
                    if (rk != rq) acc[kb][qb][r] -= 100.0f;
                }
        }
    }

#pragma unroll
    for (int qb = 0; qb < 2; ++qb) {
        float mx = acc[0][qb][0];
#pragma unroll
        for (int r = 1; r < 16; ++r) mx = fmaxf(mx, acc[0][qb][r]);
#pragma unroll
        for (int r = 0; r < 16; ++r) mx = fmaxf(mx, acc[1][qb][r]);
        mx = fmaxf(mx, __shfl_xor(mx, 32, 64));
        float sum = 0.f;
#pragma unroll
        for (int kb = 0; kb < 2; ++kb)
#pragma unroll
            for (int r = 0; r < 16; ++r) {
                float e = __expf(acc[kb][qb][r] - mx);
                acc[kb][qb][r] = e;
                sum += e;
            }
        sum += __shfl_xor(sum, 32, 64);
        float inv = 1.0f / sum;
#pragma unroll
        for (int kb = 0; kb < 2; ++kb)
#pragma unroll
            for (int r = 0; r < 16; ++r) acc[kb][qb][r] *= inv;
    }

    f32x16 o[2] = {};
#pragma unroll
    for (int ks = 0; ks < 4; ++ks) {
        const int s8 = (ks & 1) * 8, kb = ks >> 1;
        const int rb = ((lo * 64 + 16 * ks + 8 * hi) * 2) ^ ((lo & 7) << 4);
        bf16x8 vb = *(const bf16x8*)((const char*)VT + rb);
#pragma unroll
        for (int qb = 0; qb < 2; ++qb) {
            unsigned int a0 = cvtpk_bf16(acc[kb][qb][s8 + 0], acc[kb][qb][s8 + 1]);
            unsigned int b0 = cvtpk_bf16(acc[kb][qb][s8 + 4], acc[kb][qb][s8 + 5]);
            unsigned int a1 = cvtpk_bf16(acc[kb][qb][s8 + 2], acc[kb][qb][s8 + 3]);
            unsigned int b1 = cvtpk_bf16(acc[kb][qb][s8 + 6], acc[kb][qb][s8 + 7]);
            perm32swap(a0, b0);
            perm32swap(a1, b1);
            union { unsigned int u[4]; bf16x8 v; } w;
            w.u[0] = a0; w.u[1] = a1; w.u[2] = b0; w.u[3] = b1;
            o[qb] = __builtin_amdgcn_mfma_f32_32x32x16_bf16(w.v, vb, o[qb], 0, 0, 0);
        }
    }

    unsigned short* ob = out + (size_t)widx * 64 * 256 + head * 32 + lo;
#pragma unroll
    for (int qb = 0; qb < 2; ++qb)
#pragma unroll
        for (int r = 0; r < 16; ++r) {
            int q = qb * 32 + (r & 3) + 8 * (r >> 2) + 4 * hi;
            ob[(size_t)q * 256] = f2bf(o[qb][r]);
        }
}

// ---------------------------------------------------------------------------
extern "C" void kernel_launch(void* const* d_in, const int* in_sizes, int n_in,
                              void* d_out, int out_size, void* d_ws, size_t ws_size,
                              hipStream_t stream)
{
    const float* x      = (const float*)d_in[0];
    const float* ln1_g  = (const float*)d_in[1];
    const float* ln1_b  = (const float*)d_in[2];
    const float* qkv_w  = (const float*)d_in[3];
    const float* qkv_b  = (const float*)d_in[4];
    const float* proj_w = (const float*)d_in[5];
    const float* proj_b = (const float*)d_in[6];
    const float* table  = (const float*)d_in[7];
    const float* ln2_g  = (const float*)d_in[8];
    const float* ln2_b  = (const float*)d_in[9];
    const float* w1     = (const float*)d_in[10];
    const float* b1     = (const float*)d_in[11];
    const float* w2     = (const float*)d_in[12];
    const float* b2     = (const float*)d_in[13];
    const int*   relidx = (const int*)d_in[14];
    float* out = (float*)d_out;

    char* w = (char*)d_ws;
    unsigned short* xw   = (unsigned short*)w;                      // 32MB (xw -> attn_out -> ln2out)
    unsigned short* qkvb = (unsigned short*)(w + (32u << 20));      // 128MB (qkv 96MB -> mlp hidden 128MB)
    float*          h2   = (float*)(w + (160u << 20));              // 64MB
    float*          bexp = (float*)(w + (224u << 20));              // 128KB
    unsigned short* qkvT = (unsigned short*)(w + (224u << 20) + (128u << 10)); // 384KB
    unsigned short* prjT = qkvT + 768 * 256;                        // 128KB
    unsigned short* w1T  = prjT + 256 * 256;                        // 512KB
    unsigned short* w2T  = w1T + 1024 * 256;                        // 512KB

    // 0. weight transpose + bf16 convert
    convert_T_kernel<<<192, 256, 0, stream>>>(qkv_w, qkvT, 256, 768);
    convert_T_kernel<<< 64, 256, 0, stream>>>(proj_w, prjT, 256, 256);
    convert_T_kernel<<<256, 256, 0, stream>>>(w1, w1T, 256, 1024);
    convert_T_kernel<<<256, 256, 0, stream>>>(w2, w2T, 1024, 256);
    // 1. LN1 + cyclic shift + window partition (gather) -> xw bf16 [65536,256]
    ln_kernel<<<16384, 256, 0, stream>>>(x, ln1_g, ln1_b, xw, 1);
    // 1b. expand relative-position bias to [head][q][key]
    bias_expand_kernel<<<128, 256, 0, stream>>>(table, relidx, bexp);
    // 2. QKV GEMM (q cols pre-scaled by hd^-0.5) -> qkvb bf16 [65536,768]
    mgemm_kernel<1, 0, 0, 1><<<512 * 6, 256, 0, stream>>>(xw, qkvT, qkv_b, (void*)qkvb,
                                                          nullptr, 65536, 768, 256);
    // 3. MFMA window attention -> attn_out (reuse xw) bf16 [65536,256]
    attn_kernel<<<8192, 64, 0, stream>>>(qkvb, bexp, xw);
    // 4. proj GEMM + window-reverse/unshift scatter + residual(x) -> h2 f32
    mgemm_kernel<0, 0, 2, 0><<<512 * 2, 256, 0, stream>>>(xw, prjT, proj_b, (void*)h2,
                                                          x, 65536, 256, 256);
    // 5. LN2 -> ln2out (reuse xw) bf16
    ln_kernel<<<16384, 256, 0, stream>>>(h2, ln2_g, ln2_b, xw, 0);
    // 6. MLP1 GEMM + GELU -> hidden (reuse qkvb) bf16 [65536,1024]
    mgemm_kernel<1, 1, 0, 0><<<512 * 8, 256, 0, stream>>>(xw, w1T, b1, (void*)qkvb,
                                                          nullptr, 65536, 1024, 256);
    // 7. MLP2 GEMM + residual(h2) -> d_out f32
    mgemm_kernel<0, 0, 1, 0><<<512 * 2, 256, 0, stream>>>(qkvb, w2T, b2, (void*)out,
                                                          h2, 65536, 256, 1024);
}